// Round 4
// baseline (430.003 us; speedup 1.0000x reference)
//
#include <hip/hip_runtime.h>
#include <stdint.h>

#define N_NODES 1024
#define NCLS 10
#define KDIM 131072  // 1024*128

typedef unsigned short u16;
typedef __bf16 bf16x8 __attribute__((ext_vector_type(8)));
typedef float f32x4 __attribute__((ext_vector_type(4)));

__device__ __forceinline__ float b2f_lo(uint32_t u) {
  union { float f; uint32_t u; } v; v.u = u << 16; return v.f;
}
__device__ __forceinline__ float b2f_hi(uint32_t u) {
  union { float f; uint32_t u; } v; v.u = u & 0xFFFF0000u; return v.f;
}
__device__ __forceinline__ u16 f2b(float f) {
  union { float f; uint32_t u; } v; v.f = f;
  uint32_t r = v.u + 0x7FFF + ((v.u >> 16) & 1);
  return (u16)(r >> 16);
}
// packed RNE bf16 pair: hw v_cvt_pk_bf16_f32 when available (lo=arg0), manual fallback
__device__ __forceinline__ uint32_t pkbf(float a, float b) {
#if __has_builtin(__builtin_amdgcn_cvt_pk_bf16_f32)
  typedef __bf16 bf2 __attribute__((ext_vector_type(2)));
  bf2 r = __builtin_amdgcn_cvt_pk_bf16_f32(a, b);
  union { bf2 v; uint32_t u; } c; c.v = r; return c.u;
#else
  union { float f; uint32_t u; } va, vb; va.f = a; vb.f = b;
  uint32_t ra = (va.u + 0x7FFF + ((va.u >> 16) & 1)) >> 16;
  uint32_t rb = (vb.u + 0x7FFF + ((vb.u >> 16) & 1)) & 0xFFFF0000u;
  return ra | rb;
#endif
}

__device__ __forceinline__ void async_copy16(const u16* g, u16* l) {
  __builtin_amdgcn_global_load_lds(
      (const __attribute__((address_space(1))) void*)g,
      (__attribute__((address_space(3))) void*)l, 16, 0, 0);
}

// accumulate 8 bf16 (one uint4) scaled by c into float2 acc[4]
__device__ __forceinline__ void agg8(const u16* p, float c, float2* acc) {
  uint4 v = *(const uint4*)p;
  const uint32_t* u = (const uint32_t*)&v;
#pragma unroll
  for (int e = 0; e < 4; e++) {
    acc[e].x += c * b2f_lo(u[e]);
    acc[e].y += c * b2f_hi(u[e]);
  }
}

// ---------------- prep kernels ----------------
__global__ __launch_bounds__(256) void cvt_w_kernel(const float* __restrict__ w,
                                                    u16* __restrict__ o, int n) {
  int i = blockIdx.x * 256 + threadIdx.x;
  if (i < n) o[i] = f2b(w[i]);
}

__global__ __launch_bounds__(256) void prep_wc_kernel(const float* __restrict__ wc,
                                                      u16* __restrict__ o) {
  int i = blockIdx.x * 256 + threadIdx.x;  // 16*KDIM total
  int row = i >> 17;
  int col = i & (KDIM - 1);
  o[i] = (row < NCLS) ? f2b(wc[row * KDIM + col]) : (u16)0;
}

__global__ __launch_bounds__(256) void prep_tab_kernel(const float* __restrict__ adj,
                                                       int* __restrict__ nbi,
                                                       float* __restrict__ nbc,
                                                       float* __restrict__ r) {
  int m = blockIdx.x * 256 + threadIdx.x;
  if (m >= N_NODES) return;
  int i = m >> 5, j = m & 31;
  const float* arow = adj + (size_t)m * N_NODES;
  int n[5]; float c[5];
  n[0] = m;                      c[0] = arow[m];
  n[1] = (i > 0)  ? m - 32 : m;  c[1] = (i > 0)  ? arow[m - 32] : 0.f;
  n[2] = (i < 31) ? m + 32 : m;  c[2] = (i < 31) ? arow[m + 32] : 0.f;
  n[3] = (j > 0)  ? m - 1  : m;  c[3] = (j > 0)  ? arow[m - 1]  : 0.f;
  n[4] = (j < 31) ? m + 1  : m;  c[4] = (j < 31) ? arow[m + 1]  : 0.f;
  float s = 0.f;
#pragma unroll
  for (int t = 0; t < 5; t++) { nbi[m * 5 + t] = n[t]; nbc[m * 5 + t] = c[t]; s += c[t]; }
  r[m] = s;
}

__global__ __launch_bounds__(256) void outinit_kernel(const float* __restrict__ bc,
                                                      float* __restrict__ out) {
  int idx = blockIdx.x * 256 + threadIdx.x;
  if (idx < 256 * NCLS) out[idx] = bc[idx % NCLS];
}

// ---------------- fused layer1 + agg: g2 = A * relu((A x)W1^T + r.b1) ----------------
__global__ __launch_bounds__(256) void l1agg_kernel(
    const float* __restrict__ x,    // [chunk,3,1024]
    const float* __restrict__ W1,   // [256,3]
    const float* __restrict__ b1,   // [256]
    const int* __restrict__ nbi, const float* __restrict__ nbc,
    const float* __restrict__ r,    // [1024]
    u16* __restrict__ g)            // [chunk*1024, 256] = A.h1
{
  __shared__ u16 h1s[128 * 256];    // 64 KB
  __shared__ float gxs[128][4];
  __shared__ float W1s[768];
  __shared__ float b1s[256];
  int p0 = blockIdx.x * 64;
  int b = p0 >> 10;
  int m0 = p0 & 1023;
  int e0 = m0 - 32;
  int tid = threadIdx.x;

  b1s[tid] = b1[tid];
  for (int i = tid; i < 768; i += 256) W1s[i] = W1[i];

  if (tid < 128) {
    int n = e0 + tid;
    float g0 = 0.f, g1 = 0.f, g2 = 0.f, rn = 0.f;
    if (n >= 0 && n < N_NODES) {
      const float* xb = x + (size_t)b * 3072;
#pragma unroll
      for (int t = 0; t < 5; t++) {
        int nb = nbi[n * 5 + t]; float cf = nbc[n * 5 + t];
        g0 += cf * xb[nb];
        g1 += cf * xb[1024 + nb];
        g2 += cf * xb[2048 + nb];
      }
      rn = r[n];
    }
    gxs[tid][0] = g0; gxs[tid][1] = g1; gxs[tid][2] = g2; gxs[tid][3] = rn;
  }
  __syncthreads();

  int ch8 = (tid & 31) * 8;
  float w[8][3], bb[8];
#pragma unroll
  for (int c = 0; c < 8; c++) {
    w[c][0] = W1s[(ch8 + c) * 3];
    w[c][1] = W1s[(ch8 + c) * 3 + 1];
    w[c][2] = W1s[(ch8 + c) * 3 + 2];
    bb[c] = b1s[ch8 + c];
  }

#pragma unroll
  for (int it = 0; it < 16; it++) {
    int node = (tid >> 5) + it * 8;
    float g0 = gxs[node][0], g1 = gxs[node][1], g2 = gxs[node][2], rn = gxs[node][3];
    uint32_t pk[4];
#pragma unroll
    for (int c = 0; c < 8; c += 2) {
      float z0 = fmaxf(g0 * w[c][0] + g1 * w[c][1] + g2 * w[c][2] + rn * bb[c], 0.f);
      float z1 = fmaxf(g0 * w[c+1][0] + g1 * w[c+1][1] + g2 * w[c+1][2] + rn * bb[c+1], 0.f);
      pk[c >> 1] = pkbf(z0, z1);
    }
    *(uint4*)&h1s[node * 256 + ch8] = *(uint4*)pk;
  }
  __syncthreads();

#pragma unroll
  for (int it = 0; it < 8; it++) {
    int node = (tid >> 5) + it * 8;
    int m = m0 + node;
    float2 acc[4] = {};
#pragma unroll
    for (int t = 0; t < 5; t++) {
      int nb = nbi[m * 5 + t]; float cf = nbc[m * 5 + t];
      agg8(&h1s[(nb - e0) * 256 + ch8], cf, acc);
    }
    uint4 o;
    o.x = pkbf(acc[0].x, acc[0].y); o.y = pkbf(acc[1].x, acc[1].y);
    o.z = pkbf(acc[2].x, acc[2].y); o.w = pkbf(acc[3].x, acc[3].y);
    *(uint4*)&g[(size_t)(p0 + node) * 256 + ch8] = o;
  }
}

// ---------------- mm2: C = relu(A W^T + r.bias), K=256, single-shot staging ----------------
// A-tile 128x256 + B-tile 128x256 both fully staged via global_load_lds (kg-blocked,
// XOR-swizzled), ONE barrier, then 8 uninterrupted MFMA rounds. LDS = 128 KB, 1 block/CU.
__global__ __launch_bounds__(256) void mm_kernel(
    const u16* __restrict__ A, const u16* __restrict__ W,
    const float* __restrict__ bias, const float* __restrict__ r,
    u16* __restrict__ C, int N)
{
  const int K = 256;
  __shared__ u16 As[4 * 128 * 64];   // 64 KB  [kg][row][64]
  __shared__ u16 Bs[4 * 128 * 64];   // 64 KB
  int n0 = blockIdx.x * 128;
  int m0 = blockIdx.y * 128;
  int tid = threadIdx.x;
  int w = tid >> 6, l = tid & 63;
  int wm = w >> 1, wn = w & 1;

  int r8 = l >> 3, oct = l & 7;
  int so = (oct ^ r8) << 3;                 // swizzled k-offset (elements)
  const u16* ga0 = A + (size_t)(m0 + w * 32 + r8) * K + so;
  const u16* gb0 = W + (size_t)(n0 + w * 32 + r8) * K + so;

#pragma unroll
  for (int kg = 0; kg < 4; kg++)
#pragma unroll
    for (int q = 0; q < 4; q++) {
      async_copy16(ga0 + (size_t)q * 8 * K + kg * 64, &As[kg * 8192 + (w * 32 + q * 8) * 64]);
      async_copy16(gb0 + (size_t)q * 8 * K + kg * 64, &Bs[kg * 8192 + (w * 32 + q * 8) * 64]);
    }

  f32x4 acc[4][4] = {};
  int lrow = l & 15, lq = l >> 4;
  int s = lrow & 7;
  __syncthreads();

#pragma unroll
  for (int kq = 0; kq < 8; kq++) {
    int kg = kq >> 1, kh = kq & 1;
    int po = (((kh << 2) | lq) ^ s) << 3;   // physical octet offset (elements)
    bf16x8 af[4], bf[4];
#pragma unroll
    for (int t = 0; t < 4; t++) {
      af[t] = *(const bf16x8*)(&As[kg * 8192 + (wm * 64 + t * 16 + lrow) * 64 + po]);
      bf[t] = *(const bf16x8*)(&Bs[kg * 8192 + (wn * 64 + t * 16 + lrow) * 64 + po]);
    }
#pragma unroll
    for (int mt = 0; mt < 4; mt++)
#pragma unroll
      for (int nt = 0; nt < 4; nt++)
        acc[mt][nt] = __builtin_amdgcn_mfma_f32_16x16x32_bf16(af[mt], bf[nt], acc[mt][nt], 0, 0, 0);
  }

#pragma unroll
  for (int mt = 0; mt < 4; mt++)
#pragma unroll
    for (int nt = 0; nt < 4; nt++) {
      f32x4 v = acc[mt][nt];
      int col = n0 + wn * 64 + nt * 16 + lrow;
      float bs = bias[col];
#pragma unroll
      for (int i2 = 0; i2 < 4; i2++) {
        int row = m0 + wm * 64 + mt * 16 + lq * 4 + i2;
        float val = v[i2] + r[row & 1023] * bs;
        C[(size_t)row * N + col] = f2b(fmaxf(val, 0.f));
      }
    }
}

// ---------------- mm3agg: h3 = relu((A h2) W3^T + r.b3), agg hoisted out of K-loop ----------------
// Full B (128x256) via glds; full A (128x256) aggregated once into padded LDS; one barrier;
// 8 uninterrupted MFMA rounds. LDS ~130 KB, 1 block/CU.
__global__ __launch_bounds__(256) void mm3agg_kernel(
    const u16* __restrict__ H,      // h2 [chunk*1024, 256]
    const u16* __restrict__ W,      // W3b [128, 256]
    const float* __restrict__ bias, const float* __restrict__ r,
    const int* __restrict__ nbi, const float* __restrict__ nbc,
    u16* __restrict__ C)            // h3 [chunk*1024, 128]
{
  const int K = 256, N = 128;
  const int AST = 264;              // padded A row stride (elements)
  __shared__ u16 As[128 * AST];     // 67.6 KB
  __shared__ u16 Bs[4 * 128 * 64];  // 64 KB [kg][row][64]
  int m0 = blockIdx.x * 128;
  int tid = threadIdx.x;
  int w = tid >> 6, l = tid & 63;
  int wm = w >> 1, wn = w & 1;

  // B staging first (async, hidden under A aggregation)
  int r8 = l >> 3, oct = l & 7;
  int so = (oct ^ r8) << 3;
  const u16* gb0 = W + (size_t)(w * 32 + r8) * K + so;
#pragma unroll
  for (int kg = 0; kg < 4; kg++)
#pragma unroll
    for (int q = 0; q < 4; q++)
      async_copy16(gb0 + (size_t)q * 8 * K + kg * 64, &Bs[kg * 8192 + (w * 32 + q * 8) * 64]);

  // A aggregation: thread -> (row = tid/2, 128-col half), 16 units of 8 elems
  {
    int arow = tid >> 1;
    int acol0 = (tid & 1) * 128;
    int pg = m0 + arow;
    int node = pg & 1023;
    const u16* hb = H + ((size_t)(pg >> 10) << 10) * 256 + acol0;
    const u16* nbp[5]; float cf[5];
#pragma unroll
    for (int j = 0; j < 5; j++) {
      nbp[j] = hb + (size_t)nbi[node * 5 + j] * 256;
      cf[j] = nbc[node * 5 + j];
    }
    u16* dst = &As[arow * AST + acol0];
#pragma unroll 4
    for (int u = 0; u < 16; u++) {
      float2 acc[4] = {};
#pragma unroll
      for (int j = 0; j < 5; j++) agg8(nbp[j] + u * 8, cf[j], acc);
      uint4 o;
      o.x = pkbf(acc[0].x, acc[0].y); o.y = pkbf(acc[1].x, acc[1].y);
      o.z = pkbf(acc[2].x, acc[2].y); o.w = pkbf(acc[3].x, acc[3].y);
      *(uint4*)(dst + u * 8) = o;
    }
  }

  f32x4 acc[4][4] = {};
  int lrow = l & 15, lq = l >> 4;
  int s = lrow & 7;
  __syncthreads();

  const u16* pa = &As[(wm * 64 + lrow) * AST];
#pragma unroll
  for (int kq = 0; kq < 8; kq++) {
    int kg = kq >> 1, kh = kq & 1;
    int po = (((kh << 2) | lq) ^ s) << 3;
    bf16x8 af[4], bf[4];
#pragma unroll
    for (int t = 0; t < 4; t++) {
      af[t] = *(const bf16x8*)(pa + t * 16 * AST + kq * 32 + lq * 8);
      bf[t] = *(const bf16x8*)(&Bs[kg * 8192 + (wn * 64 + t * 16 + lrow) * 64 + po]);
    }
#pragma unroll
    for (int mt = 0; mt < 4; mt++)
#pragma unroll
      for (int nt = 0; nt < 4; nt++)
        acc[mt][nt] = __builtin_amdgcn_mfma_f32_16x16x32_bf16(af[mt], bf[nt], acc[mt][nt], 0, 0, 0);
  }

#pragma unroll
  for (int mt = 0; mt < 4; mt++)
#pragma unroll
    for (int nt = 0; nt < 4; nt++) {
      f32x4 v = acc[mt][nt];
      int col = wn * 64 + nt * 16 + lrow;
      float bs = bias[col];
#pragma unroll
      for (int i2 = 0; i2 < 4; i2++) {
        int row = m0 + wm * 64 + mt * 16 + lq * 4 + i2;
        float val = v[i2] + r[row & 1023] * bs;
        C[(size_t)row * N + col] = f2b(fmaxf(val, 0.f));
      }
    }
}

// ---------------- classifier ----------------
__global__ __launch_bounds__(256) void cls_kernel(
    const u16* __restrict__ h3,   // [chunk, KDIM] bf16
    const u16* __restrict__ Wcb,  // [16, KDIM] bf16 (rows 10..15 zero)
    float* __restrict__ out,      // [256, 10]
    int b0)
{
  int mt = blockIdx.x;
  int split = blockIdx.y;
  int w = threadIdx.x >> 6, l = threadIdx.x & 63;
  int lrow = l & 15, lq = l >> 4;
  f32x4 acc = {};
  int kbase = split * 4096 + w * 1024;
  const u16* pa = h3 + (size_t)(mt * 16 + lrow) * KDIM + kbase + lq * 8;
  const u16* pb = Wcb + (size_t)lrow * KDIM + kbase + lq * 8;
#pragma unroll 4
  for (int kk = 0; kk < 1024; kk += 32) {
    bf16x8 a = *(const bf16x8*)(pa + kk);
    bf16x8 b = *(const bf16x8*)(pb + kk);
    acc = __builtin_amdgcn_mfma_f32_16x16x32_bf16(a, b, acc, 0, 0, 0);
  }
  if (lrow < NCLS) {
#pragma unroll
    for (int i2 = 0; i2 < 4; i2++) {
      int b = b0 + mt * 16 + lq * 4 + i2;
      atomicAdd(&out[b * NCLS + lrow], acc[i2]);
    }
  }
}

extern "C" void kernel_launch(void* const* d_in, const int* in_sizes, int n_in,
                              void* d_out, int out_size, void* d_ws, size_t ws_size,
                              hipStream_t stream) {
  const float* x   = (const float*)d_in[0];
  const float* W1  = (const float*)d_in[1];
  const float* b1  = (const float*)d_in[2];
  const float* W2  = (const float*)d_in[3];
  const float* b2  = (const float*)d_in[4];
  const float* W3  = (const float*)d_in[5];
  const float* b3  = (const float*)d_in[6];
  const float* Wc  = (const float*)d_in[7];
  const float* bc  = (const float*)d_in[8];
  const float* adj = (const float*)d_in[9];
  float* out = (float*)d_out;
  const int B = 256;

  uint8_t* ws = (uint8_t*)d_ws;
  u16* W2b = (u16*)ws;  ws += (size_t)256 * 256 * 2;
  u16* W3b = (u16*)ws;  ws += (size_t)128 * 256 * 2;
  u16* Wcb = (u16*)ws;  ws += (size_t)16 * KDIM * 2;
  float* rr  = (float*)ws; ws += 1024 * 4;
  int*   nbi = (int*)ws;   ws += 1024 * 5 * 4;
  float* nbc = (float*)ws; ws += 1024 * 5 * 4;
  uintptr_t al = ((uintptr_t)ws + 255) & ~(uintptr_t)255;
  ws = (uint8_t*)al;
  size_t used = (size_t)(ws - (uint8_t*)d_ws);
  size_t avail = (ws_size > used) ? ws_size - used : 0;
  int chunk = 256;
  while (chunk > 32 && (size_t)chunk * 1024 * 256 * 2 * 2 > avail) chunk >>= 1;
  u16* bufA = (u16*)ws;
  u16* bufB = bufA + (size_t)chunk * 1024 * 256;

  cvt_w_kernel<<<256, 256, 0, stream>>>(W2, W2b, 256 * 256);
  cvt_w_kernel<<<128, 256, 0, stream>>>(W3, W3b, 128 * 256);
  prep_wc_kernel<<<(16 * KDIM) / 256, 256, 0, stream>>>(Wc, Wcb);
  prep_tab_kernel<<<4, 256, 0, stream>>>(adj, nbi, nbc, rr);
  outinit_kernel<<<(256 * NCLS + 255) / 256, 256, 0, stream>>>(bc, out);

  for (int b0 = 0; b0 < B; b0 += chunk) {
    const float* xb = x + (size_t)b0 * 3 * 1024;
    int M = chunk * 1024;
    // g2 = A.h1  -> bufB
    l1agg_kernel<<<M / 64, 256, 0, stream>>>(xb, W1, b1, nbi, nbc, rr, bufB);
    // h2 = relu(g2 W2^T + r.b2) -> bufA   (n-tiles adjacent in dispatch for L2 A-reuse)
    {
      dim3 g(2, M / 128);
      mm_kernel<<<g, 256, 0, stream>>>(bufB, W2b, b2, rr, bufA, 256);
    }
    // h3 = relu((A.h2) W3^T + r.b3) -> bufB
    mm3agg_kernel<<<M / 128, 256, 0, stream>>>(bufA, W3b, b3, rr, nbi, nbc, bufB);
    dim3 gc(chunk / 16, 32);
    cls_kernel<<<gc, 256, 0, stream>>>(bufB, Wcb, out, b0);
  }
}

// Round 5
// 349.572 us; speedup vs baseline: 1.2301x; 1.2301x over previous
//
#include <hip/hip_runtime.h>
#include <stdint.h>

#define N_NODES 1024
#define NCLS 10
#define KDIM 131072  // 1024*128

typedef unsigned short u16;
typedef __bf16 bf16x8 __attribute__((ext_vector_type(8)));
typedef float f32x4 __attribute__((ext_vector_type(4)));

__device__ __forceinline__ float b2f_lo(uint32_t u) {
  union { float f; uint32_t u; } v; v.u = u << 16; return v.f;
}
__device__ __forceinline__ float b2f_hi(uint32_t u) {
  union { float f; uint32_t u; } v; v.u = u & 0xFFFF0000u; return v.f;
}
__device__ __forceinline__ u16 f2b(float f) {
  union { float f; uint32_t u; } v; v.f = f;
  uint32_t r = v.u + 0x7FFF + ((v.u >> 16) & 1);
  return (u16)(r >> 16);
}
__device__ __forceinline__ uint32_t pkbf(float a, float b) {
#if __has_builtin(__builtin_amdgcn_cvt_pk_bf16_f32)
  typedef __bf16 bf2 __attribute__((ext_vector_type(2)));
  bf2 r = __builtin_amdgcn_cvt_pk_bf16_f32(a, b);
  union { bf2 v; uint32_t u; } c; c.v = r; return c.u;
#else
  union { float f; uint32_t u; } va, vb; va.f = a; vb.f = b;
  uint32_t ra = (va.u + 0x7FFF + ((va.u >> 16) & 1)) >> 16;
  uint32_t rb = (vb.u + 0x7FFF + ((vb.u >> 16) & 1)) & 0xFFFF0000u;
  return ra | rb;
#endif
}

__device__ __forceinline__ void async_copy16(const u16* g, u16* l) {
  __builtin_amdgcn_global_load_lds(
      (const __attribute__((address_space(1))) void*)g,
      (__attribute__((address_space(3))) void*)l, 16, 0, 0);
}

// accumulate 8 bf16 (one uint4) scaled by c into float2 acc[4]
__device__ __forceinline__ void agg8(uint4 v, float c, float2* acc) {
  const uint32_t* u = (const uint32_t*)&v;
#pragma unroll
  for (int e = 0; e < 4; e++) {
    acc[e].x += c * b2f_lo(u[e]);
    acc[e].y += c * b2f_hi(u[e]);
  }
}

// ---------------- prep kernels ----------------
__global__ __launch_bounds__(256) void cvt_w_kernel(const float* __restrict__ w,
                                                    u16* __restrict__ o, int n) {
  int i = blockIdx.x * 256 + threadIdx.x;
  if (i < n) o[i] = f2b(w[i]);
}

__global__ __launch_bounds__(256) void prep_wc_kernel(const float* __restrict__ wc,
                                                      u16* __restrict__ o) {
  int i = blockIdx.x * 256 + threadIdx.x;  // 16*KDIM total
  int row = i >> 17;
  int col = i & (KDIM - 1);
  o[i] = (row < NCLS) ? f2b(wc[row * KDIM + col]) : (u16)0;
}

__global__ __launch_bounds__(256) void prep_tab_kernel(const float* __restrict__ adj,
                                                       int* __restrict__ nbi,
                                                       float* __restrict__ nbc,
                                                       float* __restrict__ r) {
  int m = blockIdx.x * 256 + threadIdx.x;
  if (m >= N_NODES) return;
  int i = m >> 5, j = m & 31;
  const float* arow = adj + (size_t)m * N_NODES;
  int n[5]; float c[5];
  n[0] = m;                      c[0] = arow[m];
  n[1] = (i > 0)  ? m - 32 : m;  c[1] = (i > 0)  ? arow[m - 32] : 0.f;
  n[2] = (i < 31) ? m + 32 : m;  c[2] = (i < 31) ? arow[m + 32] : 0.f;
  n[3] = (j > 0)  ? m - 1  : m;  c[3] = (j > 0)  ? arow[m - 1]  : 0.f;
  n[4] = (j < 31) ? m + 1  : m;  c[4] = (j < 31) ? arow[m + 1]  : 0.f;
  float s = 0.f;
#pragma unroll
  for (int t = 0; t < 5; t++) { nbi[m * 5 + t] = n[t]; nbc[m * 5 + t] = c[t]; s += c[t]; }
  r[m] = s;
}

__global__ __launch_bounds__(256) void outinit_kernel(const float* __restrict__ bc,
                                                      float* __restrict__ out) {
  int idx = blockIdx.x * 256 + threadIdx.x;
  if (idx < 256 * NCLS) out[idx] = bc[idx % NCLS];
}

// ---------------- fused layer1 + agg: g2 = A * relu((A x)W1^T + r.b1) ----------------
__global__ __launch_bounds__(256) void l1agg_kernel(
    const float* __restrict__ x,    // [chunk,3,1024]
    const float* __restrict__ W1,   // [256,3]
    const float* __restrict__ b1,   // [256]
    const int* __restrict__ nbi, const float* __restrict__ nbc,
    const float* __restrict__ r,    // [1024]
    u16* __restrict__ g)            // [chunk*1024, 256] = A.h1
{
  __shared__ u16 h1s[128 * 256];    // 64 KB
  __shared__ float gxs[128][4];
  __shared__ float W1s[768];
  __shared__ float b1s[256];
  int p0 = blockIdx.x * 64;
  int b = p0 >> 10;
  int m0 = p0 & 1023;
  int e0 = m0 - 32;
  int tid = threadIdx.x;

  b1s[tid] = b1[tid];
  for (int i = tid; i < 768; i += 256) W1s[i] = W1[i];

  if (tid < 128) {
    int n = e0 + tid;
    float g0 = 0.f, g1 = 0.f, g2 = 0.f, rn = 0.f;
    if (n >= 0 && n < N_NODES) {
      const float* xb = x + (size_t)b * 3072;
#pragma unroll
      for (int t = 0; t < 5; t++) {
        int nb = nbi[n * 5 + t]; float cf = nbc[n * 5 + t];
        g0 += cf * xb[nb];
        g1 += cf * xb[1024 + nb];
        g2 += cf * xb[2048 + nb];
      }
      rn = r[n];
    }
    gxs[tid][0] = g0; gxs[tid][1] = g1; gxs[tid][2] = g2; gxs[tid][3] = rn;
  }
  __syncthreads();

  int ch8 = (tid & 31) * 8;
  float w[8][3], bb[8];
#pragma unroll
  for (int c = 0; c < 8; c++) {
    w[c][0] = W1s[(ch8 + c) * 3];
    w[c][1] = W1s[(ch8 + c) * 3 + 1];
    w[c][2] = W1s[(ch8 + c) * 3 + 2];
    bb[c] = b1s[ch8 + c];
  }

#pragma unroll
  for (int it = 0; it < 16; it++) {
    int node = (tid >> 5) + it * 8;
    float g0 = gxs[node][0], g1 = gxs[node][1], g2 = gxs[node][2], rn = gxs[node][3];
    uint32_t pk[4];
#pragma unroll
    for (int c = 0; c < 8; c += 2) {
      float z0 = fmaxf(g0 * w[c][0] + g1 * w[c][1] + g2 * w[c][2] + rn * bb[c], 0.f);
      float z1 = fmaxf(g0 * w[c+1][0] + g1 * w[c+1][1] + g2 * w[c+1][2] + rn * bb[c+1], 0.f);
      pk[c >> 1] = pkbf(z0, z1);
    }
    *(uint4*)&h1s[node * 256 + ch8] = *(uint4*)pk;
  }
  __syncthreads();

#pragma unroll
  for (int it = 0; it < 8; it++) {
    int node = (tid >> 5) + it * 8;
    int m = m0 + node;
    float2 acc[4] = {};
#pragma unroll
    for (int t = 0; t < 5; t++) {
      int nb = nbi[m * 5 + t]; float cf = nbc[m * 5 + t];
      agg8(*(const uint4*)&h1s[(nb - e0) * 256 + ch8], cf, acc);
    }
    uint4 o;
    o.x = pkbf(acc[0].x, acc[0].y); o.y = pkbf(acc[1].x, acc[1].y);
    o.z = pkbf(acc[2].x, acc[2].y); o.w = pkbf(acc[3].x, acc[3].y);
    *(uint4*)&g[(size_t)(p0 + node) * 256 + ch8] = o;
  }
}

// ---------------- mm2: C = relu(A W^T + r.bias), K=256 ----------------
// BK=64, double-buffered LDS (64 KB -> 2 blocks/CU), ONE barrier/iter;
// glds for chunk k+1 issued right after the barrier so the next barrier's
// vmcnt(0) drain only waits on loads aged by a full MFMA phase.
__global__ __launch_bounds__(256, 2) void mm_kernel(
    const u16* __restrict__ A, const u16* __restrict__ W,
    const float* __restrict__ bias, const float* __restrict__ r,
    u16* __restrict__ C, int N)
{
  const int K = 256;
  __shared__ u16 As[2][128 * 64];   // 2x16 KB
  __shared__ u16 Bs[2][128 * 64];   // 2x16 KB
  int n0 = blockIdx.x * 128;
  int m0 = blockIdx.y * 128;
  int tid = threadIdx.x;
  int w = tid >> 6, l = tid & 63;
  int wm = w >> 1, wn = w & 1;

  int r8 = l >> 3, oct = l & 7;
  int so = (oct ^ r8) << 3;                 // swizzled k-offset (elements)
  const u16* ga0 = A + (size_t)(m0 + w * 32 + r8) * K + so;
  const u16* gb0 = W + (size_t)(n0 + w * 32 + r8) * K + so;

#define MM_ISSUE(kq, buf) \
  _Pragma("unroll") for (int q = 0; q < 4; q++) { \
    async_copy16(ga0 + (size_t)q * 8 * K + (kq) * 64, &As[buf][(w * 32 + q * 8) * 64]); \
    async_copy16(gb0 + (size_t)q * 8 * K + (kq) * 64, &Bs[buf][(w * 32 + q * 8) * 64]); \
  }

  MM_ISSUE(0, 0);

  f32x4 acc[4][4] = {};
  int lrow = l & 15, lq = l >> 4;
  int s = lrow & 7;

#pragma unroll
  for (int kq = 0; kq < 4; kq++) {
    int buf = kq & 1;
    __syncthreads();
    if (kq < 3) MM_ISSUE(kq + 1, buf ^ 1);
    const u16* pa = &As[buf][(wm * 64 + lrow) * 64];
    const u16* pb = &Bs[buf][(wn * 64 + lrow) * 64];
#pragma unroll
    for (int kh = 0; kh < 2; kh++) {
      int po = (((kh << 2) | lq) ^ s) << 3;   // physical octet offset
      bf16x8 af[4], bf[4];
#pragma unroll
      for (int t = 0; t < 4; t++) {
        af[t] = *(const bf16x8*)(pa + t * 16 * 64 + po);
        bf[t] = *(const bf16x8*)(pb + t * 16 * 64 + po);
      }
#pragma unroll
      for (int mt = 0; mt < 4; mt++)
#pragma unroll
        for (int nt = 0; nt < 4; nt++)
          acc[mt][nt] = __builtin_amdgcn_mfma_f32_16x16x32_bf16(af[mt], bf[nt], acc[mt][nt], 0, 0, 0);
    }
  }
#undef MM_ISSUE

#pragma unroll
  for (int mt = 0; mt < 4; mt++)
#pragma unroll
    for (int nt = 0; nt < 4; nt++) {
      f32x4 v = acc[mt][nt];
      int col = n0 + wn * 64 + nt * 16 + lrow;
      float bs = bias[col];
#pragma unroll
      for (int i2 = 0; i2 < 4; i2++) {
        int row = m0 + wm * 64 + mt * 16 + lq * 4 + i2;
        float val = v[i2] + r[row & 1023] * bs;
        C[(size_t)row * N + col] = f2b(fmaxf(val, 0.f));
      }
    }
}

// ---------------- mm3agg: h3 = relu((A h2) W3^T + r.b3) ----------------
// Same pipelined-dbuf skeleton; the A-chunk is aggregated from register
// prefetch loads (issued after the barrier, consumed after the MFMA block,
// so the ~300-900cy global latency hides under MFMA). LDS 69 KB -> 2 blocks/CU.
__global__ __launch_bounds__(256, 2) void mm3agg_kernel(
    const u16* __restrict__ H,      // h2 [chunk*1024, 256]
    const u16* __restrict__ W,      // W3b [128, 256]
    const float* __restrict__ bias, const float* __restrict__ r,
    const int* __restrict__ nbi, const float* __restrict__ nbc,
    u16* __restrict__ C)            // h3 [chunk*1024, 128]
{
  const int K = 256, N = 128;
  const int AST = 72;               // padded A row stride (elements)
  __shared__ u16 As[2][128 * AST];  // 2x18 KB
  __shared__ u16 Bs[2][128 * 64];   // 2x16 KB
  int m0 = blockIdx.x * 128;
  int tid = threadIdx.x;
  int w = tid >> 6, l = tid & 63;
  int wm = w >> 1, wn = w & 1;

  // aggregation: thread -> (row = tid/2, 32-col half of each 64-k chunk)
  int arow = tid >> 1;
  int acol = (tid & 1) * 32;
  int pg = m0 + arow;
  int node = pg & 1023;
  const u16* hb = H + ((size_t)(pg >> 10) << 10) * 256 + acol;
  const u16* nbp[5]; float cf[5];
#pragma unroll
  for (int j = 0; j < 5; j++) {
    nbp[j] = hb + (size_t)nbi[node * 5 + j] * 256;
    cf[j] = nbc[node * 5 + j];
  }

  // B staging
  int r8 = l >> 3, oct = l & 7;
  int so = (oct ^ r8) << 3;
  const u16* gb0 = W + (size_t)(w * 32 + r8) * K + so;

#define M3_ISSUEB(kq, buf) \
  _Pragma("unroll") for (int q = 0; q < 4; q++) \
    async_copy16(gb0 + (size_t)q * 8 * K + (kq) * 64, &Bs[buf][(w * 32 + q * 8) * 64]);

#define M3_LOADA(kq) \
  _Pragma("unroll") for (int j = 0; j < 5; j++) \
    _Pragma("unroll") for (int q = 0; q < 4; q++) \
      L[j][q] = *(const uint4*)(nbp[j] + (kq) * 64 + q * 8);

#define M3_AGGSTORE(buf) { \
  u16* dst = &As[buf][arow * AST + acol]; \
  _Pragma("unroll") for (int q = 0; q < 4; q++) { \
    float2 acc2[4] = {}; \
    _Pragma("unroll") for (int j = 0; j < 5; j++) agg8(L[j][q], cf[j], acc2); \
    uint4 o; \
    o.x = pkbf(acc2[0].x, acc2[0].y); o.y = pkbf(acc2[1].x, acc2[1].y); \
    o.z = pkbf(acc2[2].x, acc2[2].y); o.w = pkbf(acc2[3].x, acc2[3].y); \
    *(uint4*)(dst + q * 8) = o; \
  } }

  uint4 L[5][4];
  M3_ISSUEB(0, 0);
  M3_LOADA(0);
  M3_AGGSTORE(0);

  f32x4 acc[4][4] = {};
  int lrow = l & 15, lq = l >> 4;
  int s = lrow & 7;

#pragma unroll
  for (int kq = 0; kq < 4; kq++) {
    int buf = kq & 1;
    __syncthreads();
    if (kq < 3) {
      M3_ISSUEB(kq + 1, buf ^ 1);
      M3_LOADA(kq + 1);               // in flight during MFMA below
    }
    const u16* pa = &As[buf][(wm * 64 + lrow) * AST];
    const u16* pb = &Bs[buf][(wn * 64 + lrow) * 64];
#pragma unroll
    for (int kh = 0; kh < 2; kh++) {
      int po = (((kh << 2) | lq) ^ s) << 3;
      bf16x8 af[4], bf[4];
#pragma unroll
      for (int t = 0; t < 4; t++) {
        af[t] = *(const bf16x8*)(pa + t * 16 * AST + kh * 32 + lq * 8);
        bf[t] = *(const bf16x8*)(pb + t * 16 * 64 + po);
      }
#pragma unroll
      for (int mt = 0; mt < 4; mt++)
#pragma unroll
        for (int nt = 0; nt < 4; nt++)
          acc[mt][nt] = __builtin_amdgcn_mfma_f32_16x16x32_bf16(af[mt], bf[nt], acc[mt][nt], 0, 0, 0);
    }
    if (kq < 3) M3_AGGSTORE(buf ^ 1);
  }
#undef M3_ISSUEB
#undef M3_LOADA
#undef M3_AGGSTORE

#pragma unroll
  for (int mt = 0; mt < 4; mt++)
#pragma unroll
    for (int nt = 0; nt < 4; nt++) {
      f32x4 v = acc[mt][nt];
      int col = wn * 64 + nt * 16 + lrow;
      float bs = bias[col];
#pragma unroll
      for (int i2 = 0; i2 < 4; i2++) {
        int row = m0 + wm * 64 + mt * 16 + lq * 4 + i2;
        float val = v[i2] + r[row & 1023] * bs;
        C[(size_t)row * N + col] = f2b(fmaxf(val, 0.f));
      }
    }
}

// ---------------- classifier ----------------
__global__ __launch_bounds__(256) void cls_kernel(
    const u16* __restrict__ h3,   // [chunk, KDIM] bf16
    const u16* __restrict__ Wcb,  // [16, KDIM] bf16 (rows 10..15 zero)
    float* __restrict__ out,      // [256, 10]
    int b0)
{
  int mt = blockIdx.x;
  int split = blockIdx.y;
  int w = threadIdx.x >> 6, l = threadIdx.x & 63;
  int lrow = l & 15, lq = l >> 4;
  f32x4 acc = {};
  int kbase = split * 4096 + w * 1024;
  const u16* pa = h3 + (size_t)(mt * 16 + lrow) * KDIM + kbase + lq * 8;
  const u16* pb = Wcb + (size_t)lrow * KDIM + kbase + lq * 8;
#pragma unroll 4
  for (int kk = 0; kk < 1024; kk += 32) {
    bf16x8 a = *(const bf16x8*)(pa + kk);
    bf16x8 b = *(const bf16x8*)(pb + kk);
    acc = __builtin_amdgcn_mfma_f32_16x16x32_bf16(a, b, acc, 0, 0, 0);
  }
  if (lrow < NCLS) {
#pragma unroll
    for (int i2 = 0; i2 < 4; i2++) {
      int b = b0 + mt * 16 + lq * 4 + i2;
      atomicAdd(&out[b * NCLS + lrow], acc[i2]);
    }
  }
}

extern "C" void kernel_launch(void* const* d_in, const int* in_sizes, int n_in,
                              void* d_out, int out_size, void* d_ws, size_t ws_size,
                              hipStream_t stream) {
  const float* x   = (const float*)d_in[0];
  const float* W1  = (const float*)d_in[1];
  const float* b1  = (const float*)d_in[2];
  const float* W2  = (const float*)d_in[3];
  const float* b2  = (const float*)d_in[4];
  const float* W3  = (const float*)d_in[5];
  const float* b3  = (const float*)d_in[6];
  const float* Wc  = (const float*)d_in[7];
  const float* bc  = (const float*)d_in[8];
  const float* adj = (const float*)d_in[9];
  float* out = (float*)d_out;
  const int B = 256;

  uint8_t* ws = (uint8_t*)d_ws;
  u16* W2b = (u16*)ws;  ws += (size_t)256 * 256 * 2;
  u16* W3b = (u16*)ws;  ws += (size_t)128 * 256 * 2;
  u16* Wcb = (u16*)ws;  ws += (size_t)16 * KDIM * 2;
  float* rr  = (float*)ws; ws += 1024 * 4;
  int*   nbi = (int*)ws;   ws += 1024 * 5 * 4;
  float* nbc = (float*)ws; ws += 1024 * 5 * 4;
  uintptr_t al = ((uintptr_t)ws + 255) & ~(uintptr_t)255;
  ws = (uint8_t*)al;
  size_t used = (size_t)(ws - (uint8_t*)d_ws);
  size_t avail = (ws_size > used) ? ws_size - used : 0;
  int chunk = 256;
  while (chunk > 32 && (size_t)chunk * 1024 * 256 * 2 * 2 > avail) chunk >>= 1;
  u16* bufA = (u16*)ws;
  u16* bufB = bufA + (size_t)chunk * 1024 * 256;

  cvt_w_kernel<<<256, 256, 0, stream>>>(W2, W2b, 256 * 256);
  cvt_w_kernel<<<128, 256, 0, stream>>>(W3, W3b, 128 * 256);
  prep_wc_kernel<<<(16 * KDIM) / 256, 256, 0, stream>>>(Wc, Wcb);
  prep_tab_kernel<<<4, 256, 0, stream>>>(adj, nbi, nbc, rr);
  outinit_kernel<<<(256 * NCLS + 255) / 256, 256, 0, stream>>>(bc, out);

  for (int b0 = 0; b0 < B; b0 += chunk) {
    const float* xb = x + (size_t)b0 * 3 * 1024;
    int M = chunk * 1024;
    // g2 = A.h1  -> bufB
    l1agg_kernel<<<M / 64, 256, 0, stream>>>(xb, W1, b1, nbi, nbc, rr, bufB);
    // h2 = relu(g2 W2^T + r.b2) -> bufA  (n-tile fastest -> adjacent blocks share A-tile in L2)
    {
      dim3 g(2, M / 128);
      mm_kernel<<<g, 256, 0, stream>>>(bufB, W2b, b2, rr, bufA, 256);
    }
    // h3 = relu((A.h2) W3^T + r.b3) -> bufB
    mm3agg_kernel<<<M / 128, 256, 0, stream>>>(bufA, W3b, b3, rr, nbi, nbc, bufB);
    dim3 gc(chunk / 16, 32);
    cls_kernel<<<gc, 256, 0, stream>>>(bufB, Wcb, out, b0);
  }
}